// Round 7
// baseline (550.720 us; speedup 1.0000x reference)
//
#include <hip/hip_runtime.h>
#include <math.h>

#define LN2F 0.69314718055994531f

typedef _Float16 v8hf __attribute__((ext_vector_type(8)));
typedef float    v4f  __attribute__((ext_vector_type(4)));

// fast shifted-softplus via v_exp_f32/v_log_f32 (~10 VALU instr vs ~50 libm).
__device__ __forceinline__ float ssp_fast(float x) {
    float e = __expf(-fabsf(x));
    return fmaxf(x, 0.f) + __logf(1.f + e) - LN2F;
}

// ---------------------------------------------------------------------------
// Prep: weights -> f16, MFMA-B-fragment order.
//   frag[((nt*KS+ks)*64 + lane)*8 + i] = W[nt*16+(lane&15)][ks*32+(lane>>4)*8+i]
// w1: 128x50 (K padded 64, KS=2); others 128x128 (KS=4).
// ---------------------------------------------------------------------------
__global__ __launch_bounds__(256)
void prep_kernel(const float* __restrict__ w1, const float* __restrict__ w2,
                 const float* __restrict__ l1w, const float* __restrict__ l2w,
                 const float* __restrict__ lw,
                 _Float16* __restrict__ w1f, _Float16* __restrict__ w2f,
                 _Float16* __restrict__ l1f, _Float16* __restrict__ l2f,
                 _Float16* __restrict__ lwf)
{
    int idx = blockIdx.x * 256 + threadIdx.x;
    if (idx < 8192) {  // w1f
        int i = idx & 7, lane = (idx >> 3) & 63, ks = (idx >> 9) & 1, nt = idx >> 10;
        int r = nt * 16 + (lane & 15);
        int k = ks * 32 + (lane >> 4) * 8 + i;
        w1f[idx] = (k < 50) ? (_Float16)w1[r * 50 + k] : (_Float16)0.f;
        return;
    }
    int o = idx - 8192;
    if (o >= 4 * 16384) return;
    int which = o >> 14;
    int p = o & 16383;
    int i = p & 7, lane = (p >> 3) & 63, ks = (p >> 9) & 3, nt = p >> 11;
    int r = nt * 16 + (lane & 15);
    int k = ks * 32 + (lane >> 4) * 8 + i;
    const float* src = (which == 0) ? w2 : (which == 1) ? l1w : (which == 2) ? l2w : lw;
    _Float16* dst   = (which == 0) ? w2f : (which == 1) ? l1f : (which == 2) ? l2f : lwf;
    dst[p] = (_Float16)src[r * 128 + k];
}

// ---------------------------------------------------------------------------
// h = X @ W^T. 32 rows/block, 4 waves = (row-half, col-half): each wave does
// 16 rows x 64 cols -> 2x the wave-parallelism of the 64-row version
// (r6 counters: node kernels grid-limited at ~10 waves/CU).
// ---------------------------------------------------------------------------
__global__ __launch_bounds__(256)
void h_gemm_kernel(const float* __restrict__ X, const _Float16* __restrict__ Wf,
                   float* __restrict__ Y, int M)
{
    const int tid = threadIdx.x, lane = tid & 63, wv = tid >> 6;
    const int rh = wv & 1, ch = wv >> 1;
    const int l15 = lane & 15, quad = lane >> 4;
    const int mb = blockIdx.x * 32 + rh * 16;

    const int mA = (mb + l15 < M) ? (mb + l15) : (M - 1);
    v8hf a[4];
    #pragma unroll
    for (int ks = 0; ks < 4; ++ks) {
        const float4* xp = (const float4*)&X[(size_t)mA * 128 + ks * 32 + quad * 8];
        float4 x0 = xp[0], x1 = xp[1];
        v8hf t = {(_Float16)x0.x, (_Float16)x0.y, (_Float16)x0.z, (_Float16)x0.w,
                  (_Float16)x1.x, (_Float16)x1.y, (_Float16)x1.z, (_Float16)x1.w};
        a[ks] = t;
    }
    #pragma unroll
    for (int nt = 0; nt < 4; ++nt) {
        const int ntg = ch * 4 + nt;
        v4f acc = {0.f, 0.f, 0.f, 0.f};
        #pragma unroll
        for (int ks = 0; ks < 4; ++ks) {
            const v8hf b = *(const v8hf*)&Wf[((ntg * 4 + ks) * 64 + lane) * 8];
            acc = __builtin_amdgcn_mfma_f32_16x16x32_f16(a[ks], b, acc, 0, 0, 0);
        }
        const int col = ntg * 16 + l15;
        #pragma unroll
        for (int r = 0; r < 4; ++r) {
            int row = mb + quad * 4 + r;
            if (row < M) Y[(size_t)row * 128 + col] = acc[r];
        }
    }
}

// ---------------------------------------------------------------------------
// Fused tail: out = ssp(agg @ l2^T + l2b) @ lw^T + lb.
// 32 rows/block, 4 waves = (row-half, col-half). Stage1 writes s into Sh
// (D-layout); cross-wave barrier; stage2 reads full-K A-frags from Sh.
// ---------------------------------------------------------------------------
__global__ __launch_bounds__(256)
void fused_out_kernel(const float* __restrict__ agg, const _Float16* __restrict__ l2f,
                      const float* __restrict__ l2b, const _Float16* __restrict__ lwf,
                      const float* __restrict__ lb, float* __restrict__ out, int M)
{
    __shared__ __align__(16) _Float16 Sh[32 * 138];
    const int tid = threadIdx.x, lane = tid & 63, wv = tid >> 6;
    const int rh = wv & 1, ch = wv >> 1;
    const int l15 = lane & 15, quad = lane >> 4;
    const int gm = blockIdx.x * 32 + rh * 16;   // this wave's global row base
    const int m0 = rh * 16;                     // local row base in Sh

    const int mA = (gm + l15 < M) ? (gm + l15) : (M - 1);
    v8hf a[4];
    #pragma unroll
    for (int ks = 0; ks < 4; ++ks) {
        const float4* xp = (const float4*)&agg[(size_t)mA * 128 + ks * 32 + quad * 8];
        float4 x0 = xp[0], x1 = xp[1];
        v8hf t = {(_Float16)x0.x, (_Float16)x0.y, (_Float16)x0.z, (_Float16)x0.w,
                  (_Float16)x1.x, (_Float16)x1.y, (_Float16)x1.z, (_Float16)x1.w};
        a[ks] = t;
    }
    #pragma unroll
    for (int nt = 0; nt < 4; ++nt) {
        const int ntg = ch * 4 + nt;
        v4f acc = {0.f, 0.f, 0.f, 0.f};
        #pragma unroll
        for (int ks = 0; ks < 4; ++ks) {
            const v8hf b = *(const v8hf*)&l2f[((ntg * 4 + ks) * 64 + lane) * 8];
            acc = __builtin_amdgcn_mfma_f32_16x16x32_f16(a[ks], b, acc, 0, 0, 0);
        }
        const float bj = l2b[ntg * 16 + l15];
        #pragma unroll
        for (int r = 0; r < 4; ++r)
            Sh[(m0 + quad * 4 + r) * 138 + ntg * 16 + l15] =
                (_Float16)ssp_fast(acc[r] + bj);
    }
    __syncthreads();   // stage2 A-frags span both col-halves' writes

    v8hf ua[4];
    #pragma unroll
    for (int ks = 0; ks < 4; ++ks)
        ua[ks] = *(const v8hf*)&Sh[(m0 + l15) * 138 + ks * 32 + quad * 8];

    #pragma unroll
    for (int nt = 0; nt < 4; ++nt) {
        const int ntg = ch * 4 + nt;
        v4f acc = {0.f, 0.f, 0.f, 0.f};
        #pragma unroll
        for (int ks = 0; ks < 4; ++ks) {
            const v8hf b = *(const v8hf*)&lwf[((ntg * 4 + ks) * 64 + lane) * 8];
            acc = __builtin_amdgcn_mfma_f32_16x16x32_f16(ua[ks], b, acc, 0, 0, 0);
        }
        const int col = ntg * 16 + l15;
        const float bj = lb[col];
        #pragma unroll
        for (int r = 0; r < 4; ++r) {
            int row = gm + quad * 4 + r;
            if (row < M) out[(size_t)row * 128 + col] = acc[r] + bj;
        }
    }
}

// ---------------------------------------------------------------------------
// Fused edge kernel (r6 structure; h-prefetch moved BEFORE attr staging so
// its latency overlaps the staging global loads too; attr loads nontemporal
// to keep L1/L2 free for the h-gather + atomic lines).
// 64 edges/block, 256 threads (4 waves x 16 edges).
// epilogue in D-layout: 16 consecutive lanes = 16 consecutive cols of ONE
// edge-row -> 64B-coalesced atomics (r2 lesson: anything else is 8x HBM).
// r4 lesson: keep the barriered structure and (256,5).
// ---------------------------------------------------------------------------
__global__ __launch_bounds__(256, 5)
void edge_kernel(const float* __restrict__ attr,  // E x 50
                 const float* __restrict__ ew,    // E
                 const int* __restrict__ srcI,
                 const int* __restrict__ dstI,
                 const _Float16* __restrict__ w1f,
                 const _Float16* __restrict__ w2f,
                 const float* __restrict__ b1,
                 const float* __restrict__ b2,
                 const float* __restrict__ h,     // N x 128
                 float* __restrict__ agg,         // N x 128 (zeroed)
                 int E)
{
    __shared__ __align__(16) _Float16 Af[64 * 64];   // A-fragment-packed attr
    __shared__ __align__(16) _Float16 Uh[64 * 138];

    const int tid = threadIdx.x;
    const int e_base = blockIdx.x * 64;
    const int lane = tid & 63, wv = tid >> 6;
    const int m0 = wv * 16, l15 = lane & 15, quad = lane >> 4;

    // ---- per-lane edge metadata (direct global; L1 broadcast) ----
    float cC[4]; const float* hrow[4]; float* arow[4]; bool val[4];
    #pragma unroll
    for (int r = 0; r < 4; ++r) {
        int eg = e_base + m0 + quad * 4 + r;
        val[r] = eg < E;
        int e = val[r] ? eg : (E - 1);
        cC[r] = 0.5f * (__cosf(ew[e] * 0.31415926535897932f) + 1.f);
        hrow[r] = h + (size_t)srcI[e] * 128;
        arow[r] = agg + (size_t)dstI[e] * 128;
    }

    // ---- h-gather prefetch FIRST: latency overlaps staging + both MFMA
    // stages. 32 VGPRs; budget 102 at the 5-block cap. ----
    float hv[8][4];
    #pragma unroll
    for (int nt = 0; nt < 8; ++nt)
        #pragma unroll
        for (int r = 0; r < 4; ++r)
            hv[nt][r] = hrow[r][nt * 16 + l15];

    // ---- stage attr -> LDS in A-fragment order (nontemporal: 128MB stream,
    // zero reuse) ----
    for (int idx = tid; idx < 4096; idx += 256) {
        int r = idx >> 6, g = idx & 63;
        int e = e_base + r;
        float v = 0.f;
        if (g < 50 && e < E) v = __builtin_nontemporal_load(&attr[(size_t)e * 50 + g]);
        Af[((((r >> 4) * 2 + (g >> 5)) * 64) + (((g & 31) >> 3) * 16) + (r & 15)) * 8
           + (g & 7)] = (_Float16)v;
    }
    __syncthreads();

    // ---- stage 1: u = ssp(attr @ W1^T + b1) -> Uh (wave-private rows) ----
    const v8hf a0 = *(const v8hf*)&Af[((wv * 2 + 0) * 64 + lane) * 8];
    const v8hf a1 = *(const v8hf*)&Af[((wv * 2 + 1) * 64 + lane) * 8];
    #pragma unroll
    for (int nt = 0; nt < 8; ++nt) {
        v4f acc = {0.f, 0.f, 0.f, 0.f};
        const v8hf bA = *(const v8hf*)&w1f[((nt * 2 + 0) * 64 + lane) * 8];
        const v8hf bB = *(const v8hf*)&w1f[((nt * 2 + 1) * 64 + lane) * 8];
        acc = __builtin_amdgcn_mfma_f32_16x16x32_f16(a0, bA, acc, 0, 0, 0);
        acc = __builtin_amdgcn_mfma_f32_16x16x32_f16(a1, bB, acc, 0, 0, 0);
        const float bj = b1[nt * 16 + l15];
        #pragma unroll
        for (int r = 0; r < 4; ++r)
            Uh[(m0 + quad * 4 + r) * 138 + nt * 16 + l15] =
                (_Float16)ssp_fast(acc[r] + bj);
    }

    // ---- stage 2 + D-layout epilogue (wave-private LDS rows) ----
    v8hf ua[4];
    #pragma unroll
    for (int ks = 0; ks < 4; ++ks)
        ua[ks] = *(const v8hf*)&Uh[(m0 + l15) * 138 + ks * 32 + quad * 8];

    #pragma unroll
    for (int nt = 0; nt < 8; ++nt) {
        v4f acc = {0.f, 0.f, 0.f, 0.f};
        #pragma unroll
        for (int ks = 0; ks < 4; ++ks) {
            const v8hf b = *(const v8hf*)&w2f[((nt * 4 + ks) * 64 + lane) * 8];
            acc = __builtin_amdgcn_mfma_f32_16x16x32_f16(ua[ks], b, acc, 0, 0, 0);
        }
        const int col = nt * 16 + l15;
        const float bj = b2[col];
        #pragma unroll
        for (int r = 0; r < 4; ++r) {
            if (val[r]) {
                float wf = (acc[r] + bj) * cC[r];
                atomicAdd(&arow[r][col], wf * hv[nt][r]);
            }
        }
    }
}

extern "C" void kernel_launch(void* const* d_in, const int* in_sizes, int n_in,
                              void* d_out, int out_size, void* d_ws, size_t ws_size,
                              hipStream_t stream)
{
    const float* x   = (const float*)d_in[0];
    const int*   ei  = (const int*)  d_in[1];
    const float* ew  = (const float*)d_in[2];
    const float* ea  = (const float*)d_in[3];
    const float* w1  = (const float*)d_in[4];
    const float* b1  = (const float*)d_in[5];
    const float* w2  = (const float*)d_in[6];
    const float* b2  = (const float*)d_in[7];
    const float* l1w = (const float*)d_in[8];
    const float* l2w = (const float*)d_in[9];
    const float* l2b = (const float*)d_in[10];
    const float* lw  = (const float*)d_in[11];
    const float* lb  = (const float*)d_in[12];

    const int N = in_sizes[0] / 128;   // 40000
    const int E = in_sizes[2];         // 640000

    float* hbuf = (float*)d_ws;                           // N*128 f32
    float* agg  = hbuf + (size_t)N * 128;                 // N*128 f32
    _Float16* w1f = (_Float16*)(agg + (size_t)N * 128);   // 8192
    _Float16* w2f = w1f + 8192;
    _Float16* l1f = w2f + 16384;
    _Float16* l2f = l1f + 16384;
    _Float16* lwf = l2f + 16384;

    const int nb32 = (N + 31) / 32;

    prep_kernel<<<288, 256, 0, stream>>>(w1, w2, l1w, l2w, lw,
                                         w1f, w2f, l1f, l2f, lwf);
    hipMemsetAsync(agg, 0, (size_t)N * 128 * sizeof(float), stream);
    h_gemm_kernel<<<nb32, 256, 0, stream>>>(x, l1f, hbuf, N);
    edge_kernel<<<(E + 63) / 64, 256, 0, stream>>>(ea, ew, ei, ei + E,
                                                   w1f, w2f, b1, b2, hbuf, agg, E);
    fused_out_kernel<<<nb32, 256, 0, stream>>>(agg, l2f, l2b, lwf, lb, (float*)d_out, N);
}